// Round 4
// baseline (601.671 us; speedup 1.0000x reference)
//
#include <hip/hip_runtime.h>

#define SEQ   2048
#define EMB   1024
#define NH    16
#define HD    64
#define BATCH 4

typedef __attribute__((ext_vector_type(8))) short short8;   // 8 bf16 = 4 VGPR
typedef __attribute__((ext_vector_type(4))) float floatx4;  // MFMA acc

// bf16 round-to-nearest-even.
static __device__ __forceinline__ ushort f2bf_rne(float x) {
  unsigned u = __float_as_uint(x);
  unsigned r = u + 0x7FFFu + ((u >> 16) & 1u);
  return (ushort)(r >> 16);
}
static __device__ __forceinline__ float bf2f(ushort h) {
  return __uint_as_float(((unsigned)h) << 16);
}

// ---------------------------------------------------------------------------
// Split-bf16 projection GEMM: Y = X @ W^T + bias (fp32 in).
// MODE 0: Q out  -> (val)*0.125, split hi/lo bf16, layout [bh, s, d]
// MODE 1: K out  -> split hi/lo bf16, layout [bh, s, d]
// MODE 2: V out  -> split hi/lo bf16, TRANSPOSED layout [bh, d, s]
// MODE 3: plain fp32 [m, n] (final output projection)
// 128x128 tile, BK=32, 256 threads = 4 waves (2x2, 64x64 out each).
// ---------------------------------------------------------------------------
template <int MODE>
__global__ __launch_bounds__(256) void proj_mfma_kernel(
    const float* __restrict__ X, const float* __restrict__ W,
    const float* __restrict__ bias, float* __restrict__ Yf,
    ushort* __restrict__ Yh, ushort* __restrict__ Yl) {
  __shared__ ushort Ahi[128 * 40], Alo[128 * 40];
  __shared__ ushort Bhi[128 * 40], Blo[128 * 40];

  const int t = threadIdx.x;
  const int lane = t & 63, wave = t >> 6;
  const int m0 = blockIdx.y * 128, n0 = blockIdx.x * 128;
  const int wm = (wave >> 1) * 64, wn = (wave & 1) * 64;
  const int fr = lane & 15, kg = lane >> 4;

  floatx4 acc[4][4];
#pragma unroll
  for (int i = 0; i < 4; ++i)
#pragma unroll
    for (int j = 0; j < 4; ++j)
#pragma unroll
      for (int r = 0; r < 4; ++r) acc[i][j][r] = 0.f;

#pragma unroll 1
  for (int k0 = 0; k0 < EMB; k0 += 32) {
    __syncthreads();
#pragma unroll
    for (int i = 0; i < 4; ++i) {
      const int f = t + 256 * i;
      const int row = f >> 3, kq = f & 7;
      {
        const float4 a =
            *(const float4*)(X + (size_t)(m0 + row) * EMB + k0 + kq * 4);
        const ushort h0 = f2bf_rne(a.x), h1 = f2bf_rne(a.y);
        const ushort h2 = f2bf_rne(a.z), h3 = f2bf_rne(a.w);
        const ushort l0 = f2bf_rne(a.x - bf2f(h0)), l1 = f2bf_rne(a.y - bf2f(h1));
        const ushort l2 = f2bf_rne(a.z - bf2f(h2)), l3 = f2bf_rne(a.w - bf2f(h3));
        uint2 hp, lp;
        hp.x = (uint)h0 | ((uint)h1 << 16);
        hp.y = (uint)h2 | ((uint)h3 << 16);
        lp.x = (uint)l0 | ((uint)l1 << 16);
        lp.y = (uint)l2 | ((uint)l3 << 16);
        *(uint2*)&Ahi[row * 40 + kq * 4] = hp;
        *(uint2*)&Alo[row * 40 + kq * 4] = lp;
      }
      {
        const float4 b =
            *(const float4*)(W + (size_t)(n0 + row) * EMB + k0 + kq * 4);
        const ushort h0 = f2bf_rne(b.x), h1 = f2bf_rne(b.y);
        const ushort h2 = f2bf_rne(b.z), h3 = f2bf_rne(b.w);
        const ushort l0 = f2bf_rne(b.x - bf2f(h0)), l1 = f2bf_rne(b.y - bf2f(h1));
        const ushort l2 = f2bf_rne(b.z - bf2f(h2)), l3 = f2bf_rne(b.w - bf2f(h3));
        uint2 hp, lp;
        hp.x = (uint)h0 | ((uint)h1 << 16);
        hp.y = (uint)h2 | ((uint)h3 << 16);
        lp.x = (uint)l0 | ((uint)l1 << 16);
        lp.y = (uint)l2 | ((uint)l3 << 16);
        *(uint2*)&Bhi[row * 40 + kq * 4] = hp;
        *(uint2*)&Blo[row * 40 + kq * 4] = lp;
      }
    }
    __syncthreads();

    short8 bhv[4], blv[4];
#pragma unroll
    for (int nf = 0; nf < 4; ++nf) {
      bhv[nf] = *(const short8*)&Bhi[(wn + nf * 16 + fr) * 40 + kg * 8];
      blv[nf] = *(const short8*)&Blo[(wn + nf * 16 + fr) * 40 + kg * 8];
    }
#pragma unroll
    for (int mf = 0; mf < 4; ++mf) {
      const short8 ah = *(const short8*)&Ahi[(wm + mf * 16 + fr) * 40 + kg * 8];
      const short8 al = *(const short8*)&Alo[(wm + mf * 16 + fr) * 40 + kg * 8];
#pragma unroll
      for (int nf = 0; nf < 4; ++nf) {
        acc[mf][nf] = __builtin_amdgcn_mfma_f32_16x16x32_bf16(ah, bhv[nf],
                                                              acc[mf][nf], 0, 0, 0);
        acc[mf][nf] = __builtin_amdgcn_mfma_f32_16x16x32_bf16(ah, blv[nf],
                                                              acc[mf][nf], 0, 0, 0);
        acc[mf][nf] = __builtin_amdgcn_mfma_f32_16x16x32_bf16(al, bhv[nf],
                                                              acc[mf][nf], 0, 0, 0);
      }
    }
  }

  // ---- epilogue: C/D layout col = lane&15, row = (lane>>4)*4 + reg ----
  const int rg = lane >> 4;
#pragma unroll
  for (int nf = 0; nf < 4; ++nf) {
    const int n = n0 + wn + nf * 16 + fr;
    const float bb = bias[n];
    if (MODE == 2) {
      // V transposed: 4 consecutive s for fixed d -> ushort4 packed stores
      const int hh = n >> 6, d = n & 63;
#pragma unroll
      for (int mf = 0; mf < 4; ++mf) {
        const int mb = m0 + wm + mf * 16 + rg * 4;
        const int b = mb >> 11, s = mb & (SEQ - 1);
        ushort4 hv, lv;
        {
          float v0 = acc[mf][nf][0] + bb, v1 = acc[mf][nf][1] + bb;
          float v2 = acc[mf][nf][2] + bb, v3 = acc[mf][nf][3] + bb;
          hv.x = f2bf_rne(v0); lv.x = f2bf_rne(v0 - bf2f(hv.x));
          hv.y = f2bf_rne(v1); lv.y = f2bf_rne(v1 - bf2f(hv.y));
          hv.z = f2bf_rne(v2); lv.z = f2bf_rne(v2 - bf2f(hv.z));
          hv.w = f2bf_rne(v3); lv.w = f2bf_rne(v3 - bf2f(hv.w));
        }
        const int idx = (b * NH + hh) * (HD * SEQ) + d * SEQ + s;
        *(ushort4*)&Yh[idx] = hv;
        *(ushort4*)&Yl[idx] = lv;
      }
    } else {
#pragma unroll
      for (int mf = 0; mf < 4; ++mf) {
#pragma unroll
        for (int r = 0; r < 4; ++r) {
          const int m = m0 + wm + mf * 16 + rg * 4 + r;
          float val = acc[mf][nf][r] + bb;
          if (MODE == 3) {
            Yf[(size_t)m * EMB + n] = val;
          } else {
            if (MODE == 0) val *= 0.125f;  // fold 1/sqrt(64) into Q
            const int hh = n >> 6, d = n & 63;
            const int b = m >> 11, s = m & (SEQ - 1);
            const int idx = ((b * NH + hh) * SEQ + s) * HD + d;
            const ushort h = f2bf_rne(val);
            Yh[idx] = h;
            Yl[idx] = f2bf_rne(val - bf2f(h));
          }
        }
      }
    }
  }
}

// ---------------------------------------------------------------------------
// Split-bf16 MFMA causal flash attention — barrier-free.
// Inputs pre-materialized bf16 hi/lo: Q (scaled) [bh,s,d], K [bh,s,d],
// Vt [bh,d,s]. Block = (bh, 128-row q-tile), 4 independent waves x 32 rows.
// K/V fragments read DIRECT from global (L2-resident); only P round-trips
// through wave-private LDS. No __syncthreads anywhere.
// ---------------------------------------------------------------------------
__global__ __launch_bounds__(256, 3) void attn_mfma_kernel(
    const ushort* __restrict__ Qh, const ushort* __restrict__ Ql,
    const ushort* __restrict__ Kh, const ushort* __restrict__ Kl,
    const ushort* __restrict__ Vth, const ushort* __restrict__ Vtl,
    float* __restrict__ O) {
  __shared__ __align__(16) ushort Phi[128 * 72], Plo[128 * 72];  // 36.9 KB

  const int bh = blockIdx.x;
  const int qt = (gridDim.y - 1) - blockIdx.y;  // heavy q-tiles first
  const int t = threadIdx.x;
  const int lane = t & 63, wave = t >> 6;
  const int fr = lane & 15, kg = lane >> 4;
  const int base = bh * (SEQ * HD);  // same for [bh,s,d] and [bh,d,s]
  const int q0 = qt * 128 + wave * 32;

  // ---- Q fragments direct from global (already scaled + split) ----
  short8 qh[2][2], ql[2][2];
#pragma unroll
  for (int mf = 0; mf < 2; ++mf)
#pragma unroll
    for (int ks = 0; ks < 2; ++ks) {
      const int idx = base + (q0 + mf * 16 + fr) * HD + ks * 32 + kg * 8;
      qh[mf][ks] = *(const short8*)&Qh[idx];
      ql[mf][ks] = *(const short8*)&Ql[idx];
    }

  floatx4 oacc[2][4];
  float m_run[2][4], l_run[2][4];
#pragma unroll
  for (int mf = 0; mf < 2; ++mf) {
#pragma unroll
    for (int nf = 0; nf < 4; ++nf)
#pragma unroll
      for (int r = 0; r < 4; ++r) oacc[mf][nf][r] = 0.f;
#pragma unroll
    for (int r = 0; r < 4; ++r) {
      m_run[mf][r] = -INFINITY;
      l_run[mf][r] = 0.f;
    }
  }

  const int my_nkt = (q0 + 95) >> 6;  // ceil((q0+32)/64) causal extent

#pragma unroll 1
  for (int kt = 0; kt < my_nkt; ++kt) {
    const int c0 = kt * 64;

    // ---- S = Q K^T (split-bf16, 3 MFMA), K frags direct from global ----
    floatx4 s[2][4];
#pragma unroll
    for (int mf = 0; mf < 2; ++mf)
#pragma unroll
      for (int nf = 0; nf < 4; ++nf)
#pragma unroll
        for (int r = 0; r < 4; ++r) s[mf][nf][r] = 0.f;

#pragma unroll
    for (int ks = 0; ks < 2; ++ks)
#pragma unroll
      for (int nf = 0; nf < 4; ++nf) {
        const int idx = base + (c0 + nf * 16 + fr) * HD + ks * 32 + kg * 8;
        const short8 kh = *(const short8*)&Kh[idx];
        const short8 kl = *(const short8*)&Kl[idx];
#pragma unroll
        for (int mf = 0; mf < 2; ++mf) {
          s[mf][nf] = __builtin_amdgcn_mfma_f32_16x16x32_bf16(
              qh[mf][ks], kh, s[mf][nf], 0, 0, 0);
          s[mf][nf] = __builtin_amdgcn_mfma_f32_16x16x32_bf16(
              qh[mf][ks], kl, s[mf][nf], 0, 0, 0);
          s[mf][nf] = __builtin_amdgcn_mfma_f32_16x16x32_bf16(
              ql[mf][ks], kh, s[mf][nf], 0, 0, 0);
        }
      }

    // ---- causal mask (edge tiles only) ----
    if (c0 + 63 > q0) {
#pragma unroll
      for (int mf = 0; mf < 2; ++mf)
#pragma unroll
        for (int nf = 0; nf < 4; ++nf)
#pragma unroll
          for (int r = 0; r < 4; ++r) {
            const int row = q0 + mf * 16 + kg * 4 + r;
            const int col = c0 + nf * 16 + fr;
            if (col > row) s[mf][nf][r] = -1e9f;
          }
    }

    // ---- online softmax + P pack to wave-private LDS ----
#pragma unroll
    for (int mf = 0; mf < 2; ++mf)
#pragma unroll
      for (int r = 0; r < 4; ++r) {
        float v0 = s[mf][0][r], v1 = s[mf][1][r];
        float v2 = s[mf][2][r], v3 = s[mf][3][r];
        float tm = fmaxf(fmaxf(v0, v1), fmaxf(v2, v3));
        tm = fmaxf(tm, __shfl_xor(tm, 1));
        tm = fmaxf(tm, __shfl_xor(tm, 2));
        tm = fmaxf(tm, __shfl_xor(tm, 4));
        tm = fmaxf(tm, __shfl_xor(tm, 8));
        const float mnew = fmaxf(m_run[mf][r], tm);
        const float alpha = __expf(m_run[mf][r] - mnew);
        m_run[mf][r] = mnew;
        const float p0 = __expf(v0 - mnew), p1 = __expf(v1 - mnew);
        const float p2 = __expf(v2 - mnew), p3 = __expf(v3 - mnew);
        float rs = p0 + p1 + p2 + p3;
        rs += __shfl_xor(rs, 1);
        rs += __shfl_xor(rs, 2);
        rs += __shfl_xor(rs, 4);
        rs += __shfl_xor(rs, 8);
        l_run[mf][r] = l_run[mf][r] * alpha + rs;
        const int qrow = wave * 32 + mf * 16 + kg * 4 + r;
        const float pv[4] = {p0, p1, p2, p3};
#pragma unroll
        for (int nf = 0; nf < 4; ++nf) {
          const ushort h = f2bf_rne(pv[nf]);
          Phi[qrow * 72 + nf * 16 + fr] = h;
          Plo[qrow * 72 + nf * 16 + fr] = f2bf_rne(pv[nf] - bf2f(h));
        }
#pragma unroll
        for (int nf = 0; nf < 4; ++nf) oacc[mf][nf][r] *= alpha;
      }

    // ---- O += P V : P from LDS, V^T frags direct from global ----
#pragma unroll
    for (int ks = 0; ks < 2; ++ks) {
      short8 ph[2], pl[2];
#pragma unroll
      for (int mf = 0; mf < 2; ++mf) {
        const int qrow = wave * 32 + mf * 16 + fr;
        ph[mf] = *(const short8*)&Phi[qrow * 72 + ks * 32 + kg * 8];
        pl[mf] = *(const short8*)&Plo[qrow * 72 + ks * 32 + kg * 8];
      }
#pragma unroll
      for (int nf = 0; nf < 4; ++nf) {
        const int d = nf * 16 + fr;
        const int idx = base + d * SEQ + c0 + ks * 32 + kg * 8;
        const short8 vh = *(const short8*)&Vth[idx];
        const short8 vl = *(const short8*)&Vtl[idx];
#pragma unroll
        for (int mf = 0; mf < 2; ++mf) {
          oacc[mf][nf] = __builtin_amdgcn_mfma_f32_16x16x32_bf16(
              ph[mf], vh, oacc[mf][nf], 0, 0, 0);
          oacc[mf][nf] = __builtin_amdgcn_mfma_f32_16x16x32_bf16(
              ph[mf], vl, oacc[mf][nf], 0, 0, 0);
          oacc[mf][nf] = __builtin_amdgcn_mfma_f32_16x16x32_bf16(
              pl[mf], vh, oacc[mf][nf], 0, 0, 0);
        }
      }
    }
  }

  // ---- epilogue: O[b, s, h*64 + d] merged fp32 layout ----
  const int b = bh >> 4, h = bh & 15;
#pragma unroll
  for (int mf = 0; mf < 2; ++mf)
#pragma unroll
    for (int r = 0; r < 4; ++r) {
      const int grow = q0 + mf * 16 + kg * 4 + r;
      const float inv = 1.f / l_run[mf][r];
      float* dst = O + (size_t)(b * SEQ + grow) * EMB + h * HD;
#pragma unroll
      for (int nf = 0; nf < 4; ++nf) dst[nf * 16 + fr] = oacc[mf][nf][r] * inv;
    }
}

// ---------------------------------------------------------------------------
extern "C" void kernel_launch(void* const* d_in, const int* in_sizes, int n_in,
                              void* d_out, int out_size, void* d_ws,
                              size_t ws_size, hipStream_t stream) {
  const float* q = (const float*)d_in[0];
  const float* k = (const float*)d_in[1];
  const float* v = (const float*)d_in[2];
  // d_in[3] = causal mask (tril by construction) -> predicate col>row instead
  const float* Wq = (const float*)d_in[4];
  const float* bq = (const float*)d_in[5];
  const float* Wk = (const float*)d_in[6];
  const float* bk = (const float*)d_in[7];
  const float* Wv = (const float*)d_in[8];
  const float* bv = (const float*)d_in[9];
  const float* Wo = (const float*)d_in[10];
  const float* bo = (const float*)d_in[11];
  float* out = (float*)d_out;

  const size_t E = (size_t)BATCH * SEQ * EMB;  // 8388608 elements
  ushort* us = (ushort*)d_ws;
  ushort* Qh = us;
  ushort* Ql = us + E;
  ushort* Kh = us + 2 * E;
  ushort* Kl = us + 3 * E;
  ushort* Vth = us + 4 * E;
  ushort* Vtl = us + 5 * E;

  const bool big = ws_size >= E * 16;  // 6 bf16 arrays + fp32 AO = 134.2 MB
  float* AO = big ? (float*)(us + 6 * E) : out;
  float* PO = big ? out : (float*)d_ws;  // !big: Qh/Ql dead once attn finishes

  const dim3 pgrid(EMB / 128, (BATCH * SEQ) / 128);  // (8, 64)
  const dim3 pblk(256);
  proj_mfma_kernel<0><<<pgrid, pblk, 0, stream>>>(q, Wq, bq, nullptr, Qh, Ql);
  proj_mfma_kernel<1><<<pgrid, pblk, 0, stream>>>(k, Wk, bk, nullptr, Kh, Kl);
  proj_mfma_kernel<2><<<pgrid, pblk, 0, stream>>>(v, Wv, bv, nullptr, Vth, Vtl);

  attn_mfma_kernel<<<dim3(BATCH * NH, SEQ / 128), 256, 0, stream>>>(
      Qh, Ql, Kh, Kl, Vth, Vtl, AO);

  proj_mfma_kernel<3><<<pgrid, pblk, 0, stream>>>(AO, Wo, bo, PO, nullptr,
                                                  nullptr);
  if (!big)
    hipMemcpyAsync(out, PO, E * sizeof(float), hipMemcpyDeviceToDevice, stream);
}

// Round 5
// 480.048 us; speedup vs baseline: 1.2534x; 1.2534x over previous
//
#include <hip/hip_runtime.h>

#define SEQ   2048
#define EMB   1024
#define NH    16
#define HD    64
#define BATCH 4

typedef __attribute__((ext_vector_type(8))) short short8;   // 8 bf16 = 4 VGPR
typedef __attribute__((ext_vector_type(4))) float floatx4;  // MFMA acc

// bf16 round-to-nearest-even.
static __device__ __forceinline__ ushort f2bf_rne(float x) {
  unsigned u = __float_as_uint(x);
  unsigned r = u + 0x7FFFu + ((u >> 16) & 1u);
  return (ushort)(r >> 16);
}
static __device__ __forceinline__ float bf2f(ushort h) {
  return __uint_as_float(((unsigned)h) << 16);
}

// Async global->LDS, 16 bytes per lane. LDS dest is wave-uniform base
// (+ lane*16 implicit); global src is per-lane.
static __device__ __forceinline__ void load16(const void* g, void* l) {
  __builtin_amdgcn_global_load_lds(
      (const __attribute__((address_space(1))) unsigned int*)g,
      (__attribute__((address_space(3))) unsigned int*)l, 16, 0, 0);
}

// ---------------------------------------------------------------------------
// Split-bf16 projection GEMM: Y = X @ W^T + bias (fp32 in).
// MODE 0: Q out  -> (val)*0.125, split hi/lo bf16, layout [bh, s, d]
// MODE 1: K out  -> split hi/lo bf16, layout [bh, s, d]
// MODE 2: V out  -> split hi/lo bf16, TRANSPOSED layout [bh, d, s]
// MODE 3: plain fp32 [m, n] (final output projection)
// ---------------------------------------------------------------------------
template <int MODE>
__global__ __launch_bounds__(256) void proj_mfma_kernel(
    const float* __restrict__ X, const float* __restrict__ W,
    const float* __restrict__ bias, float* __restrict__ Yf,
    ushort* __restrict__ Yh, ushort* __restrict__ Yl) {
  __shared__ ushort Ahi[128 * 40], Alo[128 * 40];
  __shared__ ushort Bhi[128 * 40], Blo[128 * 40];

  const int t = threadIdx.x;
  const int lane = t & 63, wave = t >> 6;
  const int m0 = blockIdx.y * 128, n0 = blockIdx.x * 128;
  const int wm = (wave >> 1) * 64, wn = (wave & 1) * 64;
  const int fr = lane & 15, kg = lane >> 4;

  floatx4 acc[4][4];
#pragma unroll
  for (int i = 0; i < 4; ++i)
#pragma unroll
    for (int j = 0; j < 4; ++j)
#pragma unroll
      for (int r = 0; r < 4; ++r) acc[i][j][r] = 0.f;

#pragma unroll 1
  for (int k0 = 0; k0 < EMB; k0 += 32) {
    __syncthreads();
#pragma unroll
    for (int i = 0; i < 4; ++i) {
      const int f = t + 256 * i;
      const int row = f >> 3, kq = f & 7;
      {
        const float4 a =
            *(const float4*)(X + (size_t)(m0 + row) * EMB + k0 + kq * 4);
        const ushort h0 = f2bf_rne(a.x), h1 = f2bf_rne(a.y);
        const ushort h2 = f2bf_rne(a.z), h3 = f2bf_rne(a.w);
        const ushort l0 = f2bf_rne(a.x - bf2f(h0)), l1 = f2bf_rne(a.y - bf2f(h1));
        const ushort l2 = f2bf_rne(a.z - bf2f(h2)), l3 = f2bf_rne(a.w - bf2f(h3));
        uint2 hp, lp;
        hp.x = (uint)h0 | ((uint)h1 << 16);
        hp.y = (uint)h2 | ((uint)h3 << 16);
        lp.x = (uint)l0 | ((uint)l1 << 16);
        lp.y = (uint)l2 | ((uint)l3 << 16);
        *(uint2*)&Ahi[row * 40 + kq * 4] = hp;
        *(uint2*)&Alo[row * 40 + kq * 4] = lp;
      }
      {
        const float4 b =
            *(const float4*)(W + (size_t)(n0 + row) * EMB + k0 + kq * 4);
        const ushort h0 = f2bf_rne(b.x), h1 = f2bf_rne(b.y);
        const ushort h2 = f2bf_rne(b.z), h3 = f2bf_rne(b.w);
        const ushort l0 = f2bf_rne(b.x - bf2f(h0)), l1 = f2bf_rne(b.y - bf2f(h1));
        const ushort l2 = f2bf_rne(b.z - bf2f(h2)), l3 = f2bf_rne(b.w - bf2f(h3));
        uint2 hp, lp;
        hp.x = (uint)h0 | ((uint)h1 << 16);
        hp.y = (uint)h2 | ((uint)h3 << 16);
        lp.x = (uint)l0 | ((uint)l1 << 16);
        lp.y = (uint)l2 | ((uint)l3 << 16);
        *(uint2*)&Bhi[row * 40 + kq * 4] = hp;
        *(uint2*)&Blo[row * 40 + kq * 4] = lp;
      }
    }
    __syncthreads();

    short8 bhv[4], blv[4];
#pragma unroll
    for (int nf = 0; nf < 4; ++nf) {
      bhv[nf] = *(const short8*)&Bhi[(wn + nf * 16 + fr) * 40 + kg * 8];
      blv[nf] = *(const short8*)&Blo[(wn + nf * 16 + fr) * 40 + kg * 8];
    }
#pragma unroll
    for (int mf = 0; mf < 4; ++mf) {
      const short8 ah = *(const short8*)&Ahi[(wm + mf * 16 + fr) * 40 + kg * 8];
      const short8 al = *(const short8*)&Alo[(wm + mf * 16 + fr) * 40 + kg * 8];
#pragma unroll
      for (int nf = 0; nf < 4; ++nf) {
        acc[mf][nf] = __builtin_amdgcn_mfma_f32_16x16x32_bf16(ah, bhv[nf],
                                                              acc[mf][nf], 0, 0, 0);
        acc[mf][nf] = __builtin_amdgcn_mfma_f32_16x16x32_bf16(ah, blv[nf],
                                                              acc[mf][nf], 0, 0, 0);
        acc[mf][nf] = __builtin_amdgcn_mfma_f32_16x16x32_bf16(al, bhv[nf],
                                                              acc[mf][nf], 0, 0, 0);
      }
    }
  }

  // ---- epilogue: C/D layout col = lane&15, row = (lane>>4)*4 + reg ----
  const int rg = lane >> 4;
#pragma unroll
  for (int nf = 0; nf < 4; ++nf) {
    const int n = n0 + wn + nf * 16 + fr;
    const float bb = bias[n];
    if (MODE == 2) {
      const int hh = n >> 6, d = n & 63;
#pragma unroll
      for (int mf = 0; mf < 4; ++mf) {
        const int mb = m0 + wm + mf * 16 + rg * 4;
        const int b = mb >> 11, s = mb & (SEQ - 1);
        ushort4 hv, lv;
        {
          float v0 = acc[mf][nf][0] + bb, v1 = acc[mf][nf][1] + bb;
          float v2 = acc[mf][nf][2] + bb, v3 = acc[mf][nf][3] + bb;
          hv.x = f2bf_rne(v0); lv.x = f2bf_rne(v0 - bf2f(hv.x));
          hv.y = f2bf_rne(v1); lv.y = f2bf_rne(v1 - bf2f(hv.y));
          hv.z = f2bf_rne(v2); lv.z = f2bf_rne(v2 - bf2f(hv.z));
          hv.w = f2bf_rne(v3); lv.w = f2bf_rne(v3 - bf2f(hv.w));
        }
        const int idx = (b * NH + hh) * (HD * SEQ) + d * SEQ + s;
        *(ushort4*)&Yh[idx] = hv;
        *(ushort4*)&Yl[idx] = lv;
      }
    } else {
#pragma unroll
      for (int mf = 0; mf < 4; ++mf) {
#pragma unroll
        for (int r = 0; r < 4; ++r) {
          const int m = m0 + wm + mf * 16 + rg * 4 + r;
          float val = acc[mf][nf][r] + bb;
          if (MODE == 3) {
            Yf[(size_t)m * EMB + n] = val;
          } else {
            if (MODE == 0) val *= 0.125f;  // fold 1/sqrt(64) into Q
            const int hh = n >> 6, d = n & 63;
            const int b = m >> 11, s = m & (SEQ - 1);
            const int idx = ((b * NH + hh) * SEQ + s) * HD + d;
            const ushort h = f2bf_rne(val);
            Yh[idx] = h;
            Yl[idx] = f2bf_rne(val - bf2f(h));
          }
        }
      }
    }
  }
}

// ---------------------------------------------------------------------------
// Split-bf16 MFMA causal flash attention — LDS-staged via global_load_lds.
// K/Vt tiles staged once per block (linear LDS dest, XOR-swizzled global
// source at 16B granularity: chunk ^= row&7) -> conflict-free ds_read_b128.
// Block = (bh, 128-row q-tile), 4 waves x 32 q-rows, kv-tile = 64.
// P round-trips via wave-private stride-72 LDS. LDS total 68.9 KB.
// ---------------------------------------------------------------------------
__global__ __launch_bounds__(256, 2) void attn_mfma_kernel(
    const ushort* __restrict__ Qh, const ushort* __restrict__ Ql,
    const ushort* __restrict__ Kh, const ushort* __restrict__ Kl,
    const ushort* __restrict__ Vth, const ushort* __restrict__ Vtl,
    float* __restrict__ O) {
  __shared__ __align__(16) ushort KHs[64 * 64], KLs[64 * 64];  // [kv][d] swz
  __shared__ __align__(16) ushort VHs[64 * 64], VLs[64 * 64];  // [d][kv] swz
  __shared__ __align__(16) ushort Phi[128 * 72], Plo[128 * 72];

  const int bh = blockIdx.x;
  const int qt = (gridDim.y - 1) - blockIdx.y;  // heavy q-tiles first
  const int t = threadIdx.x;
  const int lane = t & 63, wave = t >> 6;
  const int fr = lane & 15, kg = lane >> 4;
  const int base = bh * (SEQ * HD);  // same for [bh,s,d] and [bh,d,s]
  const int q0 = qt * 128 + wave * 32;

  // ---- Q fragments direct from global (once; already scaled + split) ----
  short8 qh[2][2], ql[2][2];
#pragma unroll
  for (int mf = 0; mf < 2; ++mf)
#pragma unroll
    for (int ks = 0; ks < 2; ++ks) {
      const int idx = base + (q0 + mf * 16 + fr) * HD + ks * 32 + kg * 8;
      qh[mf][ks] = *(const short8*)&Qh[idx];
      ql[mf][ks] = *(const short8*)&Ql[idx];
    }

  floatx4 oacc[2][4];
  float m_run[2][4], l_run[2][4];
#pragma unroll
  for (int mf = 0; mf < 2; ++mf) {
#pragma unroll
    for (int nf = 0; nf < 4; ++nf)
#pragma unroll
      for (int r = 0; r < 4; ++r) oacc[mf][nf][r] = 0.f;
#pragma unroll
    for (int r = 0; r < 4; ++r) {
      m_run[mf][r] = -INFINITY;
      l_run[mf][r] = 0.f;
    }
  }

  const int nkt = 2 * qt + 2;  // block-level causal extent
  const int r8 = lane >> 3, c8 = lane & 7;

#pragma unroll 1
  for (int kt = 0; kt < nkt; ++kt) {
    const int c0 = kt * 64;
    __syncthreads();  // prior tile's K/V reads complete before overwrite

    // ---- stage K[kv][d] and Vt[d][kv] tiles, src-swizzled, 8 instr/wave ----
#pragma unroll
    for (int i = 0; i < 2; ++i) {
      const int row = wave * 16 + i * 8 + r8;  // local kv-row / d-row, 0..63
      const int sw = ((c8 ^ (row & 7)) << 3);  // swizzled bf16 offset in row
      const int gk = base + (c0 + row) * HD + sw;
      const int gv = base + row * SEQ + c0 + sw;
      ushort* lk = (ushort*)((char*)KHs + (wave * 16 + i * 8) * 128);
      ushort* lkl = (ushort*)((char*)KLs + (wave * 16 + i * 8) * 128);
      ushort* lv = (ushort*)((char*)VHs + (wave * 16 + i * 8) * 128);
      ushort* lvl = (ushort*)((char*)VLs + (wave * 16 + i * 8) * 128);
      load16(Kh + gk, lk);
      load16(Kl + gk, lkl);
      load16(Vth + gv, lv);
      load16(Vtl + gv, lvl);
    }
    asm volatile("s_waitcnt vmcnt(0)");
    __syncthreads();

    if (c0 > q0 + 31) continue;  // fully masked for this wave

    // ---- S = Q K^T (split-bf16, 3 MFMA) ----
    floatx4 s[2][4];
#pragma unroll
    for (int mf = 0; mf < 2; ++mf)
#pragma unroll
      for (int nf = 0; nf < 4; ++nf)
#pragma unroll
        for (int r = 0; r < 4; ++r) s[mf][nf][r] = 0.f;

#pragma unroll
    for (int ks = 0; ks < 2; ++ks)
#pragma unroll
      for (int nf = 0; nf < 4; ++nf) {
        const int row = nf * 16 + fr;
        const int byo = row * 128 + (((ks * 4 + kg) ^ (row & 7)) << 4);
        const short8 kh = *(const short8*)((const char*)KHs + byo);
        const short8 kl = *(const short8*)((const char*)KLs + byo);
#pragma unroll
        for (int mf = 0; mf < 2; ++mf) {
          s[mf][nf] = __builtin_amdgcn_mfma_f32_16x16x32_bf16(
              qh[mf][ks], kh, s[mf][nf], 0, 0, 0);
          s[mf][nf] = __builtin_amdgcn_mfma_f32_16x16x32_bf16(
              qh[mf][ks], kl, s[mf][nf], 0, 0, 0);
          s[mf][nf] = __builtin_amdgcn_mfma_f32_16x16x32_bf16(
              ql[mf][ks], kh, s[mf][nf], 0, 0, 0);
        }
      }

    // ---- causal mask (edge tiles only) ----
    if (c0 + 63 > q0) {
#pragma unroll
      for (int mf = 0; mf < 2; ++mf)
#pragma unroll
        for (int nf = 0; nf < 4; ++nf)
#pragma unroll
          for (int r = 0; r < 4; ++r) {
            const int row = q0 + mf * 16 + kg * 4 + r;
            const int col = c0 + nf * 16 + fr;
            if (col > row) s[mf][nf][r] = -1e9f;
          }
    }

    // ---- online softmax + P pack to wave-private LDS ----
#pragma unroll
    for (int mf = 0; mf < 2; ++mf)
#pragma unroll
      for (int r = 0; r < 4; ++r) {
        float v0 = s[mf][0][r], v1 = s[mf][1][r];
        float v2 = s[mf][2][r], v3 = s[mf][3][r];
        float tm = fmaxf(fmaxf(v0, v1), fmaxf(v2, v3));
        tm = fmaxf(tm, __shfl_xor(tm, 1));
        tm = fmaxf(tm, __shfl_xor(tm, 2));
        tm = fmaxf(tm, __shfl_xor(tm, 4));
        tm = fmaxf(tm, __shfl_xor(tm, 8));
        const float mnew = fmaxf(m_run[mf][r], tm);
        const float alpha = __expf(m_run[mf][r] - mnew);
        m_run[mf][r] = mnew;
        const float p0 = __expf(v0 - mnew), p1 = __expf(v1 - mnew);
        const float p2 = __expf(v2 - mnew), p3 = __expf(v3 - mnew);
        float rs = p0 + p1 + p2 + p3;
        rs += __shfl_xor(rs, 1);
        rs += __shfl_xor(rs, 2);
        rs += __shfl_xor(rs, 4);
        rs += __shfl_xor(rs, 8);
        l_run[mf][r] = l_run[mf][r] * alpha + rs;
        const int qrow = wave * 32 + mf * 16 + kg * 4 + r;
        const float pv[4] = {p0, p1, p2, p3};
#pragma unroll
        for (int nf = 0; nf < 4; ++nf) {
          const ushort h = f2bf_rne(pv[nf]);
          Phi[qrow * 72 + nf * 16 + fr] = h;
          Plo[qrow * 72 + nf * 16 + fr] = f2bf_rne(pv[nf] - bf2f(h));
        }
#pragma unroll
        for (int nf = 0; nf < 4; ++nf) oacc[mf][nf][r] *= alpha;
      }

    // ---- O += P V : P from LDS, V^T frags from swizzled LDS ----
#pragma unroll
    for (int ks = 0; ks < 2; ++ks) {
      short8 ph[2], pl[2];
#pragma unroll
      for (int mf = 0; mf < 2; ++mf) {
        const int qrow = wave * 32 + mf * 16 + fr;
        ph[mf] = *(const short8*)&Phi[qrow * 72 + ks * 32 + kg * 8];
        pl[mf] = *(const short8*)&Plo[qrow * 72 + ks * 32 + kg * 8];
      }
#pragma unroll
      for (int nf = 0; nf < 4; ++nf) {
        const int d = nf * 16 + fr;
        const int byo = d * 128 + (((ks * 4 + kg) ^ (d & 7)) << 4);
        const short8 vh = *(const short8*)((const char*)VHs + byo);
        const short8 vl = *(const short8*)((const char*)VLs + byo);
#pragma unroll
        for (int mf = 0; mf < 2; ++mf) {
          oacc[mf][nf] = __builtin_amdgcn_mfma_f32_16x16x32_bf16(
              ph[mf], vh, oacc[mf][nf], 0, 0, 0);
          oacc[mf][nf] = __builtin_amdgcn_mfma_f32_16x16x32_bf16(
              ph[mf], vl, oacc[mf][nf], 0, 0, 0);
          oacc[mf][nf] = __builtin_amdgcn_mfma_f32_16x16x32_bf16(
              pl[mf], vh, oacc[mf][nf], 0, 0, 0);
        }
      }
    }
  }

  // ---- epilogue: O[b, s, h*64 + d] merged fp32 layout ----
  const int b = bh >> 4, h = bh & 15;
#pragma unroll
  for (int mf = 0; mf < 2; ++mf)
#pragma unroll
    for (int r = 0; r < 4; ++r) {
      const int grow = q0 + mf * 16 + kg * 4 + r;
      const float inv = 1.f / l_run[mf][r];
      float* dst = O + (size_t)(b * SEQ + grow) * EMB + h * HD;
#pragma unroll
      for (int nf = 0; nf < 4; ++nf) dst[nf * 16 + fr] = oacc[mf][nf][r] * inv;
    }
}

// ---------------------------------------------------------------------------
extern "C" void kernel_launch(void* const* d_in, const int* in_sizes, int n_in,
                              void* d_out, int out_size, void* d_ws,
                              size_t ws_size, hipStream_t stream) {
  const float* q = (const float*)d_in[0];
  const float* k = (const float*)d_in[1];
  const float* v = (const float*)d_in[2];
  // d_in[3] = causal mask (tril by construction) -> predicate col>row instead
  const float* Wq = (const float*)d_in[4];
  const float* bq = (const float*)d_in[5];
  const float* Wk = (const float*)d_in[6];
  const float* bk = (const float*)d_in[7];
  const float* Wv = (const float*)d_in[8];
  const float* bv = (const float*)d_in[9];
  const float* Wo = (const float*)d_in[10];
  const float* bo = (const float*)d_in[11];
  float* out = (float*)d_out;

  const size_t E = (size_t)BATCH * SEQ * EMB;  // 8388608 elements
  ushort* us = (ushort*)d_ws;
  ushort* Qh = us;
  ushort* Ql = us + E;
  ushort* Kh = us + 2 * E;
  ushort* Kl = us + 3 * E;
  ushort* Vth = us + 4 * E;
  ushort* Vtl = us + 5 * E;

  const bool big = ws_size >= E * 16;  // 6 bf16 arrays + fp32 AO = 134.2 MB
  float* AO = big ? (float*)(us + 6 * E) : out;
  float* PO = big ? out : (float*)d_ws;  // !big: Qh/Ql dead once attn finishes

  const dim3 pgrid(EMB / 128, (BATCH * SEQ) / 128);  // (8, 64)
  const dim3 pblk(256);
  proj_mfma_kernel<0><<<pgrid, pblk, 0, stream>>>(q, Wq, bq, nullptr, Qh, Ql);
  proj_mfma_kernel<1><<<pgrid, pblk, 0, stream>>>(k, Wk, bk, nullptr, Kh, Kl);
  proj_mfma_kernel<2><<<pgrid, pblk, 0, stream>>>(v, Wv, bv, nullptr, Vth, Vtl);

  attn_mfma_kernel<<<dim3(BATCH * NH, SEQ / 128), 256, 0, stream>>>(
      Qh, Ql, Kh, Kl, Vth, Vtl, AO);

  proj_mfma_kernel<3><<<pgrid, pblk, 0, stream>>>(AO, Wo, bo, PO, nullptr,
                                                  nullptr);
  if (!big)
    hipMemcpyAsync(out, PO, E * sizeof(float), hipMemcpyDeviceToDevice, stream);
}

// Round 6
// 438.411 us; speedup vs baseline: 1.3724x; 1.0950x over previous
//
#include <hip/hip_runtime.h>

#define SEQ   2048
#define EMB   1024
#define NH    16
#define HD    64
#define BATCH 4

typedef __attribute__((ext_vector_type(8))) short short8;   // 8 bf16 = 4 VGPR
typedef __attribute__((ext_vector_type(4))) float floatx4;  // MFMA acc

// bf16 round-to-nearest-even.
static __device__ __forceinline__ ushort f2bf_rne(float x) {
  unsigned u = __float_as_uint(x);
  unsigned r = u + 0x7FFFu + ((u >> 16) & 1u);
  return (ushort)(r >> 16);
}
static __device__ __forceinline__ float bf2f(ushort h) {
  return __uint_as_float(((unsigned)h) << 16);
}

// Async global->LDS, 16 bytes per lane. LDS dest must be wave-uniform base
// + lane*16 (linear); global src is per-lane.
static __device__ __forceinline__ void load16(const void* g, void* l) {
  __builtin_amdgcn_global_load_lds(
      (const __attribute__((address_space(1))) unsigned int*)g,
      (__attribute__((address_space(3))) unsigned int*)l, 16, 0, 0);
}

// Swizzled LDS byte offset for a 128x32-ushort tile staged linearly.
// Tile layout: LDS byte = line*128 + s*16 holds row=2*line+(s>>2),
// chunk c=(s&3)^(line&3) (8 ushorts). Gives minimum-phase ds_read_b128.
static __device__ __forceinline__ int swz_off(int row, int kg) {
  return (row >> 1) * 128 + (((row & 1) << 2) + (kg ^ ((row >> 1) & 3))) * 16;
}

// Stage one 128x32-ushort tile (8 KB) from pre-split global [ld=EMB] via
// global_load_lds: per-lane INVERSE-swizzled source, linear LDS dest.
static __device__ __forceinline__ void stage_tile(const ushort* __restrict__ g,
                                                  int row0, int k0,
                                                  ushort* lds, int t) {
#pragma unroll
  for (int i = 0; i < 2; ++i) {
    const int slot = t + i * 256;            // 0..511
    const int line = slot >> 3, s = slot & 7;
    const int row = line * 2 + (s >> 2);
    const int c = (s & 3) ^ (line & 3);
    load16(g + (size_t)(row0 + row) * EMB + k0 + c * 8, lds + slot * 8);
  }
}

// ---------------------------------------------------------------------------
// fp32 -> hi/lo bf16 split converter (for weight matrices). 8 elems/thread.
// ---------------------------------------------------------------------------
__global__ __launch_bounds__(256) void wconv_kernel(const float* __restrict__ W,
                                                    ushort* __restrict__ Yh,
                                                    ushort* __restrict__ Yl) {
  const int i = (blockIdx.x * 256 + threadIdx.x) * 8;
  const float4 a = *(const float4*)(W + i);
  const float4 b = *(const float4*)(W + i + 4);
  const float xv[8] = {a.x, a.y, a.z, a.w, b.x, b.y, b.z, b.w};
  uint4 hp, lp;
  uint hw[8], lw[8];
#pragma unroll
  for (int j = 0; j < 8; ++j) {
    const ushort hh = f2bf_rne(xv[j]);
    hw[j] = hh;
    lw[j] = f2bf_rne(xv[j] - bf2f(hh));
  }
  hp.x = hw[0] | (hw[1] << 16); hp.y = hw[2] | (hw[3] << 16);
  hp.z = hw[4] | (hw[5] << 16); hp.w = hw[6] | (hw[7] << 16);
  lp.x = lw[0] | (lw[1] << 16); lp.y = lw[2] | (lw[3] << 16);
  lp.z = lw[4] | (lw[5] << 16); lp.w = lw[6] | (lw[7] << 16);
  *(uint4*)&Yh[i] = hp;
  *(uint4*)&Yl[i] = lp;
}

// ---------------------------------------------------------------------------
// Split-bf16 projection GEMM: Y = X @ W^T + bias.
// PREA: A pre-split ushort [m][k] via global_load_lds (swizzled).
// PREB: B pre-split ushort [n][k] via global_load_lds (swizzled).
// !PRE*: fp32 operand, converted in-kernel to stride-40 LDS (r5 path).
// MODE 0: Q out (*0.125, hi/lo, [bh,s,d])  MODE 1: K out (hi/lo, [bh,s,d])
// MODE 2: V out (hi/lo, TRANSPOSED [bh,d,s])  MODE 3: fp32 [m,n]
// ---------------------------------------------------------------------------
template <int MODE, bool PREA, bool PREB>
__global__ __launch_bounds__(256) void proj_mfma_kernel(
    const float* __restrict__ X, const ushort* __restrict__ Xh,
    const ushort* __restrict__ Xl, const float* __restrict__ W,
    const ushort* __restrict__ Wh, const ushort* __restrict__ Wl,
    const float* __restrict__ bias, float* __restrict__ Yf,
    ushort* __restrict__ Yh, ushort* __restrict__ Yl) {
  __shared__ ushort Ahi[PREA ? 128 * 32 : 128 * 40];
  __shared__ ushort Alo[PREA ? 128 * 32 : 128 * 40];
  __shared__ ushort Bhi[PREB ? 128 * 32 : 128 * 40];
  __shared__ ushort Blo[PREB ? 128 * 32 : 128 * 40];

  const int t = threadIdx.x;
  const int lane = t & 63, wave = t >> 6;
  const int m0 = blockIdx.y * 128, n0 = blockIdx.x * 128;
  const int wm = (wave >> 1) * 64, wn = (wave & 1) * 64;
  const int fr = lane & 15, kg = lane >> 4;

  floatx4 acc[4][4];
#pragma unroll
  for (int i = 0; i < 4; ++i)
#pragma unroll
    for (int j = 0; j < 4; ++j)
#pragma unroll
      for (int r = 0; r < 4; ++r) acc[i][j][r] = 0.f;

#pragma unroll 1
  for (int k0 = 0; k0 < EMB; k0 += 32) {
    __syncthreads();
    if constexpr (PREA) {
      stage_tile(Xh, m0, k0, Ahi, t);
      stage_tile(Xl, m0, k0, Alo, t);
    } else {
#pragma unroll
      for (int i = 0; i < 4; ++i) {
        const int f = t + 256 * i;  // 1024 float4 slots = 128 rows x 8
        const int row = f >> 3, kq = f & 7;
        const float4 a =
            *(const float4*)(X + (size_t)(m0 + row) * EMB + k0 + kq * 4);
        const ushort h0 = f2bf_rne(a.x), h1 = f2bf_rne(a.y);
        const ushort h2 = f2bf_rne(a.z), h3 = f2bf_rne(a.w);
        const ushort l0 = f2bf_rne(a.x - bf2f(h0)), l1 = f2bf_rne(a.y - bf2f(h1));
        const ushort l2 = f2bf_rne(a.z - bf2f(h2)), l3 = f2bf_rne(a.w - bf2f(h3));
        uint2 hp, lp;
        hp.x = (uint)h0 | ((uint)h1 << 16);
        hp.y = (uint)h2 | ((uint)h3 << 16);
        lp.x = (uint)l0 | ((uint)l1 << 16);
        lp.y = (uint)l2 | ((uint)l3 << 16);
        *(uint2*)&Ahi[row * 40 + kq * 4] = hp;
        *(uint2*)&Alo[row * 40 + kq * 4] = lp;
      }
    }
    if constexpr (PREB) {
      stage_tile(Wh, n0, k0, Bhi, t);
      stage_tile(Wl, n0, k0, Blo, t);
    } else {
#pragma unroll
      for (int i = 0; i < 4; ++i) {
        const int f = t + 256 * i;
        const int row = f >> 3, kq = f & 7;
        const float4 b =
            *(const float4*)(W + (size_t)(n0 + row) * EMB + k0 + kq * 4);
        const ushort h0 = f2bf_rne(b.x), h1 = f2bf_rne(b.y);
        const ushort h2 = f2bf_rne(b.z), h3 = f2bf_rne(b.w);
        const ushort l0 = f2bf_rne(b.x - bf2f(h0)), l1 = f2bf_rne(b.y - bf2f(h1));
        const ushort l2 = f2bf_rne(b.z - bf2f(h2)), l3 = f2bf_rne(b.w - bf2f(h3));
        uint2 hp, lp;
        hp.x = (uint)h0 | ((uint)h1 << 16);
        hp.y = (uint)h2 | ((uint)h3 << 16);
        lp.x = (uint)l0 | ((uint)l1 << 16);
        lp.y = (uint)l2 | ((uint)l3 << 16);
        *(uint2*)&Bhi[row * 40 + kq * 4] = hp;
        *(uint2*)&Blo[row * 40 + kq * 4] = lp;
      }
    }
    if constexpr (PREA || PREB) asm volatile("s_waitcnt vmcnt(0)");
    __syncthreads();

    short8 bhv[4], blv[4];
#pragma unroll
    for (int nf = 0; nf < 4; ++nf) {
      const int row = wn + nf * 16 + fr;
      if constexpr (PREB) {
        const int off = swz_off(row, kg);
        bhv[nf] = *(const short8*)((const char*)Bhi + off);
        blv[nf] = *(const short8*)((const char*)Blo + off);
      } else {
        bhv[nf] = *(const short8*)&Bhi[row * 40 + kg * 8];
        blv[nf] = *(const short8*)&Blo[row * 40 + kg * 8];
      }
    }
#pragma unroll
    for (int mf = 0; mf < 4; ++mf) {
      const int arow = wm + mf * 16 + fr;
      short8 ah, al;
      if constexpr (PREA) {
        const int off = swz_off(arow, kg);
        ah = *(const short8*)((const char*)Ahi + off);
        al = *(const short8*)((const char*)Alo + off);
      } else {
        ah = *(const short8*)&Ahi[arow * 40 + kg * 8];
        al = *(const short8*)&Alo[arow * 40 + kg * 8];
      }
#pragma unroll
      for (int nf = 0; nf < 4; ++nf) {
        acc[mf][nf] = __builtin_amdgcn_mfma_f32_16x16x32_bf16(ah, bhv[nf],
                                                              acc[mf][nf], 0, 0, 0);
        acc[mf][nf] = __builtin_amdgcn_mfma_f32_16x16x32_bf16(ah, blv[nf],
                                                              acc[mf][nf], 0, 0, 0);
        acc[mf][nf] = __builtin_amdgcn_mfma_f32_16x16x32_bf16(al, bhv[nf],
                                                              acc[mf][nf], 0, 0, 0);
      }
    }
  }

  // ---- epilogue: C/D layout col = lane&15, row = (lane>>4)*4 + reg ----
  const int rg = lane >> 4;
#pragma unroll
  for (int nf = 0; nf < 4; ++nf) {
    const int n = n0 + wn + nf * 16 + fr;
    const float bb = bias[n];
    if (MODE == 2) {
      const int hh = n >> 6, d = n & 63;
#pragma unroll
      for (int mf = 0; mf < 4; ++mf) {
        const int mb = m0 + wm + mf * 16 + rg * 4;
        const int b = mb >> 11, s = mb & (SEQ - 1);
        ushort4 hv, lv;
        {
          float v0 = acc[mf][nf][0] + bb, v1 = acc[mf][nf][1] + bb;
          float v2 = acc[mf][nf][2] + bb, v3 = acc[mf][nf][3] + bb;
          hv.x = f2bf_rne(v0); lv.x = f2bf_rne(v0 - bf2f(hv.x));
          hv.y = f2bf_rne(v1); lv.y = f2bf_rne(v1 - bf2f(hv.y));
          hv.z = f2bf_rne(v2); lv.z = f2bf_rne(v2 - bf2f(hv.z));
          hv.w = f2bf_rne(v3); lv.w = f2bf_rne(v3 - bf2f(hv.w));
        }
        const int idx = (b * NH + hh) * (HD * SEQ) + d * SEQ + s;
        *(ushort4*)&Yh[idx] = hv;
        *(ushort4*)&Yl[idx] = lv;
      }
    } else {
#pragma unroll
      for (int mf = 0; mf < 4; ++mf) {
#pragma unroll
        for (int r = 0; r < 4; ++r) {
          const int m = m0 + wm + mf * 16 + rg * 4 + r;
          float val = acc[mf][nf][r] + bb;
          if (MODE == 3) {
            Yf[(size_t)m * EMB + n] = val;
          } else {
            if (MODE == 0) val *= 0.125f;  // fold 1/sqrt(64) into Q
            const int hh = n >> 6, d = n & 63;
            const int b = m >> 11, s = m & (SEQ - 1);
            const int idx = ((b * NH + hh) * SEQ + s) * HD + d;
            const ushort h = f2bf_rne(val);
            Yh[idx] = h;
            Yl[idx] = f2bf_rne(val - bf2f(h));
          }
        }
      }
    }
  }
}

// ---------------------------------------------------------------------------
// Split-bf16 MFMA causal flash attention (r5 structure, unchanged numerics).
// SPLITOUT: epilogue emits AO as hi/lo bf16 [m][e] (bit-identical to the
// conversion the O-proj previously did on fp32 AO); else fp32 merged layout.
// ---------------------------------------------------------------------------
template <bool SPLITOUT>
__global__ __launch_bounds__(256, 2) void attn_mfma_kernel(
    const ushort* __restrict__ Qh, const ushort* __restrict__ Ql,
    const ushort* __restrict__ Kh, const ushort* __restrict__ Kl,
    const ushort* __restrict__ Vth, const ushort* __restrict__ Vtl,
    float* __restrict__ O, ushort* __restrict__ Oh, ushort* __restrict__ Ol) {
  __shared__ __align__(16) ushort KHs[64 * 64], KLs[64 * 64];  // [kv][d] swz
  __shared__ __align__(16) ushort VHs[64 * 64], VLs[64 * 64];  // [d][kv] swz
  __shared__ __align__(16) ushort Phi[128 * 72], Plo[128 * 72];

  const int bh = blockIdx.x;
  const int qt = (gridDim.y - 1) - blockIdx.y;  // heavy q-tiles first
  const int t = threadIdx.x;
  const int lane = t & 63, wave = t >> 6;
  const int fr = lane & 15, kg = lane >> 4;
  const int base = bh * (SEQ * HD);  // same for [bh,s,d] and [bh,d,s]
  const int q0 = qt * 128 + wave * 32;

  // ---- Q fragments direct from global (once; already scaled + split) ----
  short8 qh[2][2], ql[2][2];
#pragma unroll
  for (int mf = 0; mf < 2; ++mf)
#pragma unroll
    for (int ks = 0; ks < 2; ++ks) {
      const int idx = base + (q0 + mf * 16 + fr) * HD + ks * 32 + kg * 8;
      qh[mf][ks] = *(const short8*)&Qh[idx];
      ql[mf][ks] = *(const short8*)&Ql[idx];
    }

  floatx4 oacc[2][4];
  float m_run[2][4], l_run[2][4];
#pragma unroll
  for (int mf = 0; mf < 2; ++mf) {
#pragma unroll
    for (int nf = 0; nf < 4; ++nf)
#pragma unroll
      for (int r = 0; r < 4; ++r) oacc[mf][nf][r] = 0.f;
#pragma unroll
    for (int r = 0; r < 4; ++r) {
      m_run[mf][r] = -INFINITY;
      l_run[mf][r] = 0.f;
    }
  }

  const int nkt = 2 * qt + 2;  // block-level causal extent
  const int r8 = lane >> 3, c8 = lane & 7;

#pragma unroll 1
  for (int kt = 0; kt < nkt; ++kt) {
    const int c0 = kt * 64;
    __syncthreads();  // prior tile's K/V reads complete before overwrite

    // ---- stage K[kv][d] and Vt[d][kv] tiles, src-swizzled ----
#pragma unroll
    for (int i = 0; i < 2; ++i) {
      const int row = wave * 16 + i * 8 + r8;  // local kv-row / d-row, 0..63
      const int sw = ((c8 ^ (row & 7)) << 3);  // swizzled bf16 offset in row
      const int gk = base + (c0 + row) * HD + sw;
      const int gv = base + row * SEQ + c0 + sw;
      ushort* lk = (ushort*)((char*)KHs + (wave * 16 + i * 8) * 128);
      ushort* lkl = (ushort*)((char*)KLs + (wave * 16 + i * 8) * 128);
      ushort* lv = (ushort*)((char*)VHs + (wave * 16 + i * 8) * 128);
      ushort* lvl = (ushort*)((char*)VLs + (wave * 16 + i * 8) * 128);
      load16(Kh + gk, lk);
      load16(Kl + gk, lkl);
      load16(Vth + gv, lv);
      load16(Vtl + gv, lvl);
    }
    asm volatile("s_waitcnt vmcnt(0)");
    __syncthreads();

    if (c0 > q0 + 31) continue;  // fully masked for this wave

    // ---- S = Q K^T (split-bf16, 3 MFMA) ----
    floatx4 s[2][4];
#pragma unroll
    for (int mf = 0; mf < 2; ++mf)
#pragma unroll
      for (int nf = 0; nf < 4; ++nf)
#pragma unroll
        for (int r = 0; r < 4; ++r) s[mf][nf][r] = 0.f;

#pragma unroll
    for (int ks = 0; ks < 2; ++ks)
#pragma unroll
      for (int nf = 0; nf < 4; ++nf) {
        const int row = nf * 16 + fr;
        const int byo = row * 128 + (((ks * 4 + kg) ^ (row & 7)) << 4);
        const short8 kh = *(const short8*)((const char*)KHs + byo);
        const short8 kl = *(const short8*)((const char*)KLs + byo);
#pragma unroll
        for (int mf = 0; mf < 2; ++mf) {
          s[mf][nf] = __builtin_amdgcn_mfma_f32_16x16x32_bf16(
              qh[mf][ks], kh, s[mf][nf], 0, 0, 0);
          s[mf][nf] = __builtin_amdgcn_mfma_f32_16x16x32_bf16(
              qh[mf][ks], kl, s[mf][nf], 0, 0, 0);
          s[mf][nf] = __builtin_amdgcn_mfma_f32_16x16x32_bf16(
              ql[mf][ks], kh, s[mf][nf], 0, 0, 0);
        }
      }

    // ---- causal mask (edge tiles only) ----
    if (c0 + 63 > q0) {
#pragma unroll
      for (int mf = 0; mf < 2; ++mf)
#pragma unroll
        for (int nf = 0; nf < 4; ++nf)
#pragma unroll
          for (int r = 0; r < 4; ++r) {
            const int row = q0 + mf * 16 + kg * 4 + r;
            const int col = c0 + nf * 16 + fr;
            if (col > row) s[mf][nf][r] = -1e9f;
          }
    }

    // ---- online softmax + P pack to wave-private LDS ----
#pragma unroll
    for (int mf = 0; mf < 2; ++mf)
#pragma unroll
      for (int r = 0; r < 4; ++r) {
        float v0 = s[mf][0][r], v1 = s[mf][1][r];
        float v2 = s[mf][2][r], v3 = s[mf][3][r];
        float tm = fmaxf(fmaxf(v0, v1), fmaxf(v2, v3));
        tm = fmaxf(tm, __shfl_xor(tm, 1));
        tm = fmaxf(tm, __shfl_xor(tm, 2));
        tm = fmaxf(tm, __shfl_xor(tm, 4));
        tm = fmaxf(tm, __shfl_xor(tm, 8));
        const float mnew = fmaxf(m_run[mf][r], tm);
        const float alpha = __expf(m_run[mf][r] - mnew);
        m_run[mf][r] = mnew;
        const float p0 = __expf(v0 - mnew), p1 = __expf(v1 - mnew);
        const float p2 = __expf(v2 - mnew), p3 = __expf(v3 - mnew);
        float rs = p0 + p1 + p2 + p3;
        rs += __shfl_xor(rs, 1);
        rs += __shfl_xor(rs, 2);
        rs += __shfl_xor(rs, 4);
        rs += __shfl_xor(rs, 8);
        l_run[mf][r] = l_run[mf][r] * alpha + rs;
        const int qrow = wave * 32 + mf * 16 + kg * 4 + r;
        const float pv[4] = {p0, p1, p2, p3};
#pragma unroll
        for (int nf = 0; nf < 4; ++nf) {
          const ushort h = f2bf_rne(pv[nf]);
          Phi[qrow * 72 + nf * 16 + fr] = h;
          Plo[qrow * 72 + nf * 16 + fr] = f2bf_rne(pv[nf] - bf2f(h));
        }
#pragma unroll
        for (int nf = 0; nf < 4; ++nf) oacc[mf][nf][r] *= alpha;
      }

    // ---- O += P V : P from LDS, V^T frags from swizzled LDS ----
#pragma unroll
    for (int ks = 0; ks < 2; ++ks) {
      short8 ph[2], pl[2];
#pragma unroll
      for (int mf = 0; mf < 2; ++mf) {
        const int qrow = wave * 32 + mf * 16 + fr;
        ph[mf] = *(const short8*)&Phi[qrow * 72 + ks * 32 + kg * 8];
        pl[mf] = *(const short8*)&Plo[qrow * 72 + ks * 32 + kg * 8];
      }
#pragma unroll
      for (int nf = 0; nf < 4; ++nf) {
        const int d = nf * 16 + fr;
        const int byo = d * 128 + (((ks * 4 + kg) ^ (d & 7)) << 4);
        const short8 vh = *(const short8*)((const char*)VHs + byo);
        const short8 vl = *(const short8*)((const char*)VLs + byo);
#pragma unroll
        for (int mf = 0; mf < 2; ++mf) {
          oacc[mf][nf] = __builtin_amdgcn_mfma_f32_16x16x32_bf16(
              ph[mf], vh, oacc[mf][nf], 0, 0, 0);
          oacc[mf][nf] = __builtin_amdgcn_mfma_f32_16x16x32_bf16(
              ph[mf], vl, oacc[mf][nf], 0, 0, 0);
          oacc[mf][nf] = __builtin_amdgcn_mfma_f32_16x16x32_bf16(
              pl[mf], vh, oacc[mf][nf], 0, 0, 0);
        }
      }
    }
  }

  // ---- epilogue: AO[m = b*SEQ+s][e = h*64+d] ----
  const int b = bh >> 4, hsel = bh & 15;
#pragma unroll
  for (int mf = 0; mf < 2; ++mf)
#pragma unroll
    for (int r = 0; r < 4; ++r) {
      const int grow = q0 + mf * 16 + kg * 4 + r;
      const float inv = 1.f / l_run[mf][r];
      const int rowbase = (b * SEQ + grow) * EMB + hsel * HD;
#pragma unroll
      for (int nf = 0; nf < 4; ++nf) {
        const float val = oacc[mf][nf][r] * inv;
        const int idx = rowbase + nf * 16 + fr;
        if constexpr (SPLITOUT) {
          const ushort hh = f2bf_rne(val);
          Oh[idx] = hh;
          Ol[idx] = f2bf_rne(val - bf2f(hh));
        } else {
          O[idx] = val;
        }
      }
    }
}

// ---------------------------------------------------------------------------
extern "C" void kernel_launch(void* const* d_in, const int* in_sizes, int n_in,
                              void* d_out, int out_size, void* d_ws,
                              size_t ws_size, hipStream_t stream) {
  const float* q = (const float*)d_in[0];
  const float* k = (const float*)d_in[1];
  const float* v = (const float*)d_in[2];
  // d_in[3] = causal mask (tril by construction) -> predicate col>row instead
  const float* Wq = (const float*)d_in[4];
  const float* bq = (const float*)d_in[5];
  const float* Wk = (const float*)d_in[6];
  const float* bk = (const float*)d_in[7];
  const float* Wv = (const float*)d_in[8];
  const float* bv = (const float*)d_in[9];
  const float* Wo = (const float*)d_in[10];
  const float* bo = (const float*)d_in[11];
  float* out = (float*)d_out;

  const size_t E = (size_t)BATCH * SEQ * EMB;  // 8388608 elements
  const size_t WE = (size_t)EMB * EMB;         // 1048576 elements
  ushort* us = (ushort*)d_ws;
  ushort* Qh = us;
  ushort* Ql = us + E;
  ushort* Kh = us + 2 * E;
  ushort* Kl = us + 3 * E;
  ushort* Vth = us + 4 * E;
  ushort* Vtl = us + 5 * E;

  const dim3 pgrid(EMB / 128, (BATCH * SEQ) / 128);  // (8, 64)
  const dim3 agrid(BATCH * NH, SEQ / 128);
  const dim3 blk(256);
  const int wgrid = (int)(WE / 8 / 256);  // 512 blocks per weight matrix

  if (ws_size >= 8 * E * sizeof(ushort)) {
    // ---- Tier A (ws >= 134.2 MB) ----
    // Phase 1: W3 conversions live in the (not-yet-used) AO region [6E..8E).
    ushort* W3 = us + 6 * E;
    ushort* Wqh = W3, *Wql = W3 + WE;
    ushort* Wkh = W3 + 2 * WE, *Wkl = W3 + 3 * WE;
    ushort* Wvh = W3 + 4 * WE, *Wvl = W3 + 5 * WE;
    ushort* AOh = us + 6 * E, *AOl = us + 7 * E;  // overwrites W3 post-projs
    ushort* Woh = us, *Wol = us + WE;             // Qh region, dead post-attn

    wconv_kernel<<<wgrid, blk, 0, stream>>>(Wq, Wqh, Wql);
    wconv_kernel<<<wgrid, blk, 0, stream>>>(Wk, Wkh, Wkl);
    wconv_kernel<<<wgrid, blk, 0, stream>>>(Wv, Wvh, Wvl);
    proj_mfma_kernel<0, false, true><<<pgrid, blk, 0, stream>>>(
        q, nullptr, nullptr, nullptr, Wqh, Wql, bq, nullptr, Qh, Ql);
    proj_mfma_kernel<1, false, true><<<pgrid, blk, 0, stream>>>(
        k, nullptr, nullptr, nullptr, Wkh, Wkl, bk, nullptr, Kh, Kl);
    proj_mfma_kernel<2, false, true><<<pgrid, blk, 0, stream>>>(
        v, nullptr, nullptr, nullptr, Wvh, Wvl, bv, nullptr, Vth, Vtl);
    attn_mfma_kernel<true><<<agrid, blk, 0, stream>>>(Qh, Ql, Kh, Kl, Vth, Vtl,
                                                      nullptr, AOh, AOl);
    wconv_kernel<<<wgrid, blk, 0, stream>>>(Wo, Woh, Wol);
    proj_mfma_kernel<3, true, true><<<pgrid, blk, 0, stream>>>(
        nullptr, AOh, AOl, nullptr, Woh, Wol, bo, out, nullptr, nullptr);
  } else if (ws_size >= (6 * E + 6 * WE) * sizeof(ushort)) {
    // ---- Tier B (ws >= 113.3 MB): AO hi/lo lives in `out` ----
    ushort* W3 = us + 6 * E;
    ushort* Wqh = W3, *Wql = W3 + WE;
    ushort* Wkh = W3 + 2 * WE, *Wkl = W3 + 3 * WE;
    ushort* Wvh = W3 + 4 * WE, *Wvl = W3 + 5 * WE;
    ushort* AOh = (ushort*)d_out, *AOl = AOh + E;  // 2E ushort == out bytes
    ushort* Woh = us, *Wol = us + WE;              // Qh region, dead
    float* PO = (float*)(us + 2 * E);              // Kh/Kl region, dead

    wconv_kernel<<<wgrid, blk, 0, stream>>>(Wq, Wqh, Wql);
    wconv_kernel<<<wgrid, blk, 0, stream>>>(Wk, Wkh, Wkl);
    wconv_kernel<<<wgrid, blk, 0, stream>>>(Wv, Wvh, Wvl);
    proj_mfma_kernel<0, false, true><<<pgrid, blk, 0, stream>>>(
        q, nullptr, nullptr, nullptr, Wqh, Wql, bq, nullptr, Qh, Ql);
    proj_mfma_kernel<1, false, true><<<pgrid, blk, 0, stream>>>(
        k, nullptr, nullptr, nullptr, Wkh, Wkl, bk, nullptr, Kh, Kl);
    proj_mfma_kernel<2, false, true><<<pgrid, blk, 0, stream>>>(
        v, nullptr, nullptr, nullptr, Wvh, Wvl, bv, nullptr, Vth, Vtl);
    attn_mfma_kernel<true><<<agrid, blk, 0, stream>>>(Qh, Ql, Kh, Kl, Vth, Vtl,
                                                      nullptr, AOh, AOl);
    wconv_kernel<<<wgrid, blk, 0, stream>>>(Wo, Woh, Wol);
    proj_mfma_kernel<3, true, true><<<pgrid, blk, 0, stream>>>(
        nullptr, AOh, AOl, nullptr, Woh, Wol, bo, PO, nullptr, nullptr);
    hipMemcpyAsync(out, PO, E * sizeof(float), hipMemcpyDeviceToDevice, stream);
  } else {
    // ---- Tier C: exact r5 behavior (in-kernel W conversion, fp32 AO) ----
    float* AO = out;
    float* PO = (float*)d_ws;  // Qh/Ql region, dead once attn finishes
    proj_mfma_kernel<0, false, false><<<pgrid, blk, 0, stream>>>(
        q, nullptr, nullptr, Wq, nullptr, nullptr, bq, nullptr, Qh, Ql);
    proj_mfma_kernel<1, false, false><<<pgrid, blk, 0, stream>>>(
        k, nullptr, nullptr, Wk, nullptr, nullptr, bk, nullptr, Kh, Kl);
    proj_mfma_kernel<2, false, false><<<pgrid, blk, 0, stream>>>(
        v, nullptr, nullptr, Wv, nullptr, nullptr, bv, nullptr, Vth, Vtl);
    attn_mfma_kernel<false><<<agrid, blk, 0, stream>>>(
        Qh, Ql, Kh, Kl, Vth, Vtl, AO, nullptr, nullptr);
    proj_mfma_kernel<3, false, false><<<pgrid, blk, 0, stream>>>(
        AO, nullptr, nullptr, Wo, nullptr, nullptr, bo, PO, nullptr, nullptr);
    hipMemcpyAsync(out, PO, E * sizeof(float), hipMemcpyDeviceToDevice, stream);
  }
}